// Round 7
// baseline (87.800 us; speedup 1.0000x reference)
//
#include <hip/hip_runtime.h>

#define DEV __device__ __forceinline__

typedef __bf16 bf16;
typedef __bf16 bf16x8 __attribute__((ext_vector_type(8)));
typedef __bf16 bf16x4 __attribute__((ext_vector_type(4)));
typedef float f32x4 __attribute__((ext_vector_type(4)));

#define B_ 2
#define D_ 512
#define N_ 2048
#define H_ 8
#define MD_ 64
// 1/sqrt(512) * log2(e): scores pre-scaled so softmax uses exp2 directly
#define SCALE_F (0.04419417382415922f * 1.4426950408889634f)

DEV void gload_lds16(const void* g, void* l) {
  __builtin_amdgcn_global_load_lds(
      (const __attribute__((address_space(1))) void*)g,
      (__attribute__((address_space(3))) void*)l, 16, 0, 0);
}

DEV f32x4 mfma16(bf16x8 a, bf16x8 b, f32x4 c) {
  return __builtin_amdgcn_mfma_f32_16x16x32_bf16(a, b, c, 0, 0, 0);
}

// ---------------------------------------------------------------------------
// prep_w: rows 0..1535 -> Wf bf16 (Wq*SCALE | Wk | Wv), bias_f (bq*SCALE|bk|bv)
//         rows 1536..2047 -> Wo_r[r][h*64+d] = Wo[r][d*8+h]  (bf16)
// ---------------------------------------------------------------------------
__global__ __launch_bounds__(256) void prep_w(
    const float* __restrict__ Wq, const float* __restrict__ bq,
    const float* __restrict__ Wk, const float* __restrict__ bk,
    const float* __restrict__ Wv, const float* __restrict__ bv,
    const float* __restrict__ Wo,
    bf16* __restrict__ Wf, float* __restrict__ biasf, bf16* __restrict__ Wor) {
  int row = blockIdx.x;
  int t = threadIdx.x;
  if (row < 1536) {
    const float* src;
    float scale = 1.0f;
    if (row < 512)       { src = Wq + (size_t)row * 512; scale = SCALE_F; }
    else if (row < 1024) { src = Wk + (size_t)(row - 512) * 512; }
    else                 { src = Wv + (size_t)(row - 1024) * 512; }
    for (int c = t; c < 512; c += 256)
      Wf[(size_t)row * 512 + c] = (bf16)(src[c] * scale);
    if (t == 0) {
      float bb;
      if (row < 512)       bb = bq[row] * SCALE_F;
      else if (row < 1024) bb = bk[row - 512];
      else                 bb = bv[row - 1024];
      biasf[row] = bb;
    }
  } else {
    int r = row - 1536;
    for (int c2 = t; c2 < 512; c2 += 256) {
      int hh = c2 >> 6, dd = c2 & 63;
      Wor[(size_t)r * 512 + c2] = (bf16)Wo[(size_t)r * 512 + dd * 8 + hh];
    }
  }
}

// ---------------------------------------------------------------------------
// prep_qt: Qt[b][n][c] = bf16(Q[b][c][n])   (64x64 tiles through LDS)
// grid (N/64, D/64, B), block 256
// ---------------------------------------------------------------------------
__global__ __launch_bounds__(256) void prep_qt(const float* __restrict__ Q,
                                               bf16* __restrict__ Qt) {
  __shared__ float tile[64][65];
  int b = blockIdx.z;
  int d0 = blockIdx.y * 64;
  int n0 = blockIdx.x * 64;
  int t = threadIdx.x;
  int r = t >> 2, cw = t & 3;

  const float* src = Q + ((size_t)(b * 512 + d0 + r)) * 2048 + n0 + cw * 16;
#pragma unroll
  for (int e4 = 0; e4 < 4; ++e4) {
    float4 v = *(const float4*)(src + e4 * 4);
    tile[r][cw * 16 + e4 * 4 + 0] = v.x;
    tile[r][cw * 16 + e4 * 4 + 1] = v.y;
    tile[r][cw * 16 + e4 * 4 + 2] = v.z;
    tile[r][cw * 16 + e4 * 4 + 3] = v.w;
  }
  __syncthreads();
  bf16x8 o0{}, o1{};
#pragma unroll
  for (int e = 0; e < 8; ++e) {
    o0[e] = (bf16)tile[cw * 16 + e][r];
    o1[e] = (bf16)tile[cw * 16 + 8 + e][r];
  }
  bf16* dst = Qt + ((size_t)(b * 2048 + n0 + r)) * 512 + d0 + cw * 16;
  *(bf16x8*)dst = o0;
  *((bf16x8*)dst + 1) = o1;
}

// ---------------------------------------------------------------------------
// qkv_gemm v3: 128x64 tiles, double-buffered LDS, 1 barrier per K-step.
// grid (12, 32, 2) = 768 blocks = 3/CU even. 4 waves 2x2, BK=32.
// C[c][p] = sum_k Wf[c][k] * Qt[b][p][k] + bias[c]
// Epilogue: c<512 -> qp[b][h][p][d]; c<1024 -> kp; else vn[b][c][p]
// ---------------------------------------------------------------------------
__global__ __launch_bounds__(256) void qkv_gemm(
    const bf16* __restrict__ Wf, const bf16* __restrict__ Qt,
    const float* __restrict__ biasf,
    bf16* __restrict__ qp, bf16* __restrict__ kp, bf16* __restrict__ vn) {
  __shared__ bf16 Al[2][128 * 32];
  __shared__ bf16 Bl[2][64 * 32];
  int b = blockIdx.z;
  int c0 = blockIdx.x * 128;
  int p0 = blockIdx.y * 64;
  int tid = threadIdx.x, w = tid >> 6, lane = tid & 63;
  int wm = w >> 1, wn = w & 1;
  int g = lane >> 4, l15 = lane & 15;

  const bf16* Abase = Wf + (size_t)c0 * 512;
  const bf16* Bbase = Qt + ((size_t)b * 2048 + p0) * 512;

  int arow0 = lane >> 2;           // 0..15 within a 16-row group
  int ach = lane & 3;

  f32x4 acc[4][2] = {};

  // prologue: stage ks=0 into buf 0
#pragma unroll
  for (int i = 0; i < 2; ++i)
    gload_lds16(Abase + (size_t)(w * 32 + i * 16 + arow0) * 512 + ach * 8,
                Al[0] + (w * 32 + i * 16) * 32);
  gload_lds16(Bbase + (size_t)(w * 16 + arow0) * 512 + ach * 8,
              Bl[0] + w * 16 * 32);
  __syncthreads();

  for (int ks = 0; ks < 16; ++ks) {
    int cur = ks & 1, nxt = cur ^ 1;
    if (ks < 15) {
      int k0 = (ks + 1) * 32;
#pragma unroll
      for (int i = 0; i < 2; ++i)
        gload_lds16(Abase + (size_t)(w * 32 + i * 16 + arow0) * 512 + k0 + ach * 8,
                    Al[nxt] + (w * 32 + i * 16) * 32);
      gload_lds16(Bbase + (size_t)(w * 16 + arow0) * 512 + k0 + ach * 8,
                  Bl[nxt] + w * 16 * 32);
    }
    bf16x8 a[4], bb[2];
#pragma unroll
    for (int mi = 0; mi < 4; ++mi)
      a[mi] = *(const bf16x8*)(Al[cur] + (wm * 64 + mi * 16 + l15) * 32 + g * 8);
#pragma unroll
    for (int ni = 0; ni < 2; ++ni)
      bb[ni] = *(const bf16x8*)(Bl[cur] + (wn * 32 + ni * 16 + l15) * 32 + g * 8);
#pragma unroll
    for (int mi = 0; mi < 4; ++mi)
#pragma unroll
      for (int ni = 0; ni < 2; ++ni)
        acc[mi][ni] = mfma16(a[mi], bb[ni], acc[mi][ni]);
    __syncthreads();
  }

#pragma unroll
  for (int mi = 0; mi < 4; ++mi) {
#pragma unroll
    for (int ni = 0; ni < 2; ++ni) {
#pragma unroll
      for (int r = 0; r < 4; ++r) {
        int row = c0 + wm * 64 + mi * 16 + g * 4 + r;
        int p = p0 + wn * 32 + ni * 16 + l15;
        float val = acc[mi][ni][r] + biasf[row];
        bf16 hv = (bf16)val;
        if (row < 512) {
          int c = row;
          qp[(((size_t)b * 8 + (c & 7)) * 2048 + p) * 64 + (c >> 3)] = hv;
        } else if (row < 1024) {
          int c = row - 512;
          kp[(((size_t)b * 8 + (c & 7)) * 2048 + p) * 64 + (c >> 3)] = hv;
        } else {
          int c = row - 1024;
          vn[((size_t)b * 512 + c) * 2048 + p] = hv;
        }
      }
    }
  }
}

// ---------------------------------------------------------------------------
// attn_k v7: QBLK=128, 4 waves x 32 q-rows (two 16-row groups/wave) -> each
// staged K/V tile read serves 2x the q-rows (LDS-read-bound fix).
// KV-split x2, grid (16, 16, 2), block 256. Swapped QK^T softmax (per-lane
// m/l scalars per group). K/V dbuf, 1 barrier/step, setprio on MFMA.
// Writes unnormalized O-partial (bf16) + per-row m,l (f32, log2 domain).
// LDS: 2*8(K)+2*8(V)+16(Ps) = 48KB.
// ---------------------------------------------------------------------------
__global__ __launch_bounds__(256) void attn_k(
    const bf16* __restrict__ qp, const bf16* __restrict__ kp,
    const bf16* __restrict__ vn, bf16* __restrict__ Op,
    float* __restrict__ mbuf, float* __restrict__ lbuf) {
  __shared__ bf16 Ks[2][64 * 64];
  __shared__ bf16 Vs[2][64 * 64];
  __shared__ bf16 Ps[128 * 64];
  int q0 = blockIdx.x * 128;
  int bh = blockIdx.y;            // b*8 + h
  int z = blockIdx.z;             // kv split
  int b = bh >> 3, h = bh & 7;
  int tid = threadIdx.x, w = tid >> 6, lane = tid & 63;
  int g = lane >> 4, l15 = lane & 15;

  // Q B-fragments for both row groups (reused all 16 steps)
  bf16x8 qreg[2][2];
#pragma unroll
  for (int rg = 0; rg < 2; ++rg)
#pragma unroll
    for (int ks2 = 0; ks2 < 2; ++ks2)
      qreg[rg][ks2] = *(const bf16x8*)(
          qp + ((size_t)bh * 2048 + q0 + w * 32 + rg * 16 + l15) * 64 +
          ks2 * 32 + g * 8);

  // staging: 256 threads x 16B = 4KB per issue; 2 issues cover a 64x64 tile.
  // thread covers rows (tid>>3) + i*32; swizzled source chunk, linear dest.
  int krow = tid >> 3;            // 0..31
  int kch = tid & 7;

  const bf16* Kall = kp + (size_t)bh * 2048 * 64 + (size_t)z * 16 * 64 * 64;
  const bf16* Vall = vn + ((size_t)(b * 512 + h)) * 2048 + (size_t)z * 16 * 64;

  // stage K/V local step 0 into buffer 0
#pragma unroll
  for (int i = 0; i < 2; ++i) {
    int row = krow + i * 32;
    int ch = kch ^ (row & 7);
    gload_lds16(Kall + (size_t)row * 64 + ch * 8, Ks[0] + (w * 8 + i * 32) * 64);
    gload_lds16(Vall + (size_t)row * 16384 + ch * 8, Vs[0] + (w * 8 + i * 32) * 64);
  }

  f32x4 oacc[2][4] = {};
  float mrow[2] = {-1e30f, -1e30f}, rs[2] = {0.0f, 0.0f};

  __syncthreads();  // step-0 staging drained (vmcnt(0) inside)

  for (int t = 0; t < 16; ++t) {
    int cur = t & 1, nxt = cur ^ 1;
    int tn = (t < 15) ? t + 1 : 15;  // clamp (redundant last prefetch)

    // issue next-step staging (lands during compute; drained at loop-end sync)
#pragma unroll
    for (int i = 0; i < 2; ++i) {
      int row = krow + i * 32;
      int ch = kch ^ (row & 7);
      gload_lds16(Kall + (size_t)tn * 4096 + (size_t)row * 64 + ch * 8,
                  Ks[nxt] + (w * 8 + i * 32) * 64);
      gload_lds16(Vall + (size_t)tn * 64 + (size_t)row * 16384 + ch * 8,
                  Vs[nxt] + (w * 8 + i * 32) * 64);
    }

    // S^T = K Q^T for both groups: st[rg][jt][i] = S[q][j=jt*16+g*4+i]
    f32x4 st[2][4] = {};
    __builtin_amdgcn_s_setprio(1);
#pragma unroll
    for (int ks2 = 0; ks2 < 2; ++ks2) {
#pragma unroll
      for (int jt = 0; jt < 4; ++jt) {
        int jrow = jt * 16 + l15;
        bf16x8 kb = *(const bf16x8*)(Ks[cur] + jrow * 64 +
                                     (((ks2 * 4 + g) ^ (jrow & 7)) << 3));
        st[0][jt] = mfma16(kb, qreg[0][ks2], st[0][jt]);
        st[1][jt] = mfma16(kb, qreg[1][ks2], st[1][jt]);
      }
    }
    __builtin_amdgcn_s_setprio(0);

    // per-lane row max per group (15 fmax) + 2 shfl_xor across g-copies
    float rm[2];
#pragma unroll
    for (int rg = 0; rg < 2; ++rg) {
      float m0 = st[rg][0][0];
#pragma unroll
      for (int jt = 0; jt < 4; ++jt)
#pragma unroll
        for (int i = 0; i < 4; ++i) m0 = fmaxf(m0, st[rg][jt][i]);
      m0 = fmaxf(m0, __shfl_xor(m0, 16));
      m0 = fmaxf(m0, __shfl_xor(m0, 32));
      rm[rg] = m0;
    }

    if (__any(fmaxf(rm[0] - mrow[0], rm[1] - mrow[1]) > 8.0f)) {
#pragma unroll
      for (int rg = 0; rg < 2; ++rg) {
        float nm = fmaxf(mrow[rg], rm[rg]);
        float esc = __builtin_amdgcn_exp2f(mrow[rg] - nm);
        mrow[rg] = nm;
        rs[rg] *= esc;
#pragma unroll
        for (int r = 0; r < 4; ++r) {
          float er = __shfl(esc, g * 4 + r, 64);
#pragma unroll
          for (int dt = 0; dt < 4; ++dt) oacc[rg][dt][r] *= er;
        }
      }
    }

    // P = exp2(S - m): 4 consecutive j per jt -> ds_write_b64 per (rg,jt)
#pragma unroll
    for (int rg = 0; rg < 2; ++rg) {
      int prow = w * 32 + rg * 16 + l15;
#pragma unroll
      for (int jt = 0; jt < 4; ++jt) {
        bf16x4 pk;
#pragma unroll
        for (int i = 0; i < 4; ++i) {
          float pv = __builtin_amdgcn_exp2f(st[rg][jt][i] - mrow[rg]);
          rs[rg] += pv;
          pk[i] = (bf16)pv;
        }
        *(bf16x4*)(Ps + prow * 64 + ((jt * 16 + g * 4) ^ ((prow & 7) << 3))) = pk;
      }
    }

    // O += P V  (Ps rows wave-private: lgkmcnt ordering only, no barrier)
    __builtin_amdgcn_s_setprio(1);
#pragma unroll
    for (int ks2 = 0; ks2 < 2; ++ks2) {
      int r0w = w * 32 + l15;
      int r1w = w * 32 + 16 + l15;
      bf16x8 pa0 = *(const bf16x8*)(Ps + r0w * 64 +
                                    (((ks2 * 4 + g) ^ (r0w & 7)) << 3));
      bf16x8 pa1 = *(const bf16x8*)(Ps + r1w * 64 +
                                    (((ks2 * 4 + g) ^ (r1w & 7)) << 3));
#pragma unroll
      for (int dt = 0; dt < 4; ++dt) {
        int drow = dt * 16 + l15;
        bf16x8 vb = *(const bf16x8*)(Vs[cur] + drow * 64 +
                                     (((ks2 * 4 + g) ^ (drow & 7)) << 3));
        oacc[0][dt] = mfma16(pa0, vb, oacc[0][dt]);
        oacc[1][dt] = mfma16(pa1, vb, oacc[1][dt]);
      }
    }
    __builtin_amdgcn_s_setprio(0);

    __syncthreads();  // drains next-step staging + releases buf[cur]
  }

  // full row sums (combine the 4 g-copies)
#pragma unroll
  for (int rg = 0; rg < 2; ++rg) {
    rs[rg] += __shfl_xor(rs[rg], 16);
    rs[rg] += __shfl_xor(rs[rg], 32);
  }

  // epilogue: UNNORMALIZED partial O (bf16) + m,l per row
  size_t zoff = (size_t)z * 16 * 2048;
#pragma unroll
  for (int rg = 0; rg < 2; ++rg) {
#pragma unroll
    for (int dt = 0; dt < 4; ++dt) {
#pragma unroll
      for (int r = 0; r < 4; ++r) {
        int i = w * 32 + rg * 16 + g * 4 + r;
        Op[(zoff + (size_t)bh * 2048 + q0 + i) * 64 + dt * 16 + l15] =
            (bf16)oacc[rg][dt][r];
      }
    }
  }
  if (lane < 16) {  // g==0: one lane per q-row per group
#pragma unroll
    for (int rg = 0; rg < 2; ++rg) {
      int i = w * 32 + rg * 16 + l15;
      mbuf[zoff + (size_t)bh * 2048 + q0 + i] = mrow[rg];
      lbuf[zoff + (size_t)bh * 2048 + q0 + i] = rs[rg];
    }
  }
}

// ---------------------------------------------------------------------------
// combine: oh[row][d] = (w0*O0 + w1*O1) / (w0*l0 + w1*l1), w_z = 2^(m_z - M)
// 131072 threads: thread = (row, 16-d chunk). grid 512, block 256.
// ---------------------------------------------------------------------------
__global__ __launch_bounds__(256) void combine(
    const bf16* __restrict__ Op, const float* __restrict__ mbuf,
    const float* __restrict__ lbuf, bf16* __restrict__ oh) {
  int idx = blockIdx.x * 256 + threadIdx.x;
  int row = idx >> 2;
  int dc = (idx & 3) * 16;
  float m0 = mbuf[row], m1 = mbuf[32768 + row];
  float l0 = lbuf[row], l1 = lbuf[32768 + row];
  float M = fmaxf(m0, m1);
  float w0 = __builtin_amdgcn_exp2f(m0 - M);
  float w1 = __builtin_amdgcn_exp2f(m1 - M);
  float invL = 1.0f / (w0 * l0 + w1 * l1);
  float a0 = w0 * invL, a1 = w1 * invL;

  const bf16x8* p0 = (const bf16x8*)(Op + (size_t)row * 64 + dc);
  const bf16x8* p1 = (const bf16x8*)(Op + (size_t)32768 * 64 + (size_t)row * 64 + dc);
  bf16x8* po = (bf16x8*)(oh + (size_t)row * 64 + dc);
#pragma unroll
  for (int v = 0; v < 2; ++v) {
    bf16x8 x0 = p0[v], x1 = p1[v];
    bf16x8 o;
#pragma unroll
    for (int e = 0; e < 8; ++e)
      o[e] = (bf16)(a0 * (float)x0[e] + a1 * (float)x1[e]);
    po[v] = o;
  }
}

// ---------------------------------------------------------------------------
// out_gemm v3: 128x64 tiles, double-buffered LDS, 1 barrier per K-step.
// grid (4, 32, 2) = 256 blocks. 4 waves 2x2, BK=32.
// out[b][r][p] = sum_k Wor[r][k] * oh_as_B[p][k] + bo[r]   (fp32 out)
// ---------------------------------------------------------------------------
__global__ __launch_bounds__(256) void out_gemm(
    const bf16* __restrict__ Wor, const bf16* __restrict__ oh,
    const float* __restrict__ bo, float* __restrict__ out) {
  __shared__ bf16 Al[2][128 * 32];
  __shared__ bf16 Bl[2][64 * 32];
  int b = blockIdx.z;
  int r0 = blockIdx.x * 128;
  int p0 = blockIdx.y * 64;
  int tid = threadIdx.x, w = tid >> 6, lane = tid & 63;
  int wm = w >> 1, wn = w & 1;
  int g = lane >> 4, l15 = lane & 15;

  const bf16* Abase = Wor + (size_t)r0 * 512;
  const bf16* Bhead = oh + (size_t)b * 8 * 2048 * 64 + (size_t)p0 * 64;

  int arow0 = lane >> 2;
  int ach = lane & 3;

  f32x4 acc[4][2] = {};

  // k-step ks covers k0 = ks*32: B rows live at oh[b][k0>>6][p][k0&63 ..]
#pragma unroll
  for (int i = 0; i < 2; ++i)
    gload_lds16(Abase + (size_t)(w * 32 + i * 16 + arow0) * 512 + ach * 8,
                Al[0] + (w * 32 + i * 16) * 32);
  gload_lds16(Bhead + (size_t)(w * 16 + arow0) * 64 + ach * 8,
              Bl[0] + w * 16 * 32);
  __syncthreads();

  for (int ks = 0; ks < 16; ++ks) {
    int cur = ks & 1, nxt = cur ^ 1;
    if (ks < 15) {
      int k0 = (ks + 1) * 32;
      const bf16* Bbase = Bhead + (size_t)(k0 >> 6) * 2048 * 64 + (k0 & 63);
#pragma unroll
      for (int i = 0; i < 2; ++i)
        gload_lds16(Abase + (size_t)(w * 32 + i * 16 + arow0) * 512 + k0 + ach * 8,
                    Al[nxt] + (w * 32 + i * 16) * 32);
      gload_lds16(Bbase + (size_t)(w * 16 + arow0) * 64 + ach * 8,
                  Bl[nxt] + w * 16 * 32);
    }
    bf16x8 a[4], bb[2];
#pragma unroll
    for (int mi = 0; mi < 4; ++mi)
      a[mi] = *(const bf16x8*)(Al[cur] + (wm * 64 + mi * 16 + l15) * 32 + g * 8);
#pragma unroll
    for (int ni = 0; ni < 2; ++ni)
      bb[ni] = *(const bf16x8*)(Bl[cur] + (wn * 32 + ni * 16 + l15) * 32 + g * 8);
#pragma unroll
    for (int mi = 0; mi < 4; ++mi)
#pragma unroll
      for (int ni = 0; ni < 2; ++ni)
        acc[mi][ni] = mfma16(a[mi], bb[ni], acc[mi][ni]);
    __syncthreads();
  }

#pragma unroll
  for (int mi = 0; mi < 4; ++mi) {
#pragma unroll
    for (int ni = 0; ni < 2; ++ni) {
#pragma unroll
      for (int r = 0; r < 4; ++r) {
        int row = r0 + wm * 64 + mi * 16 + g * 4 + r;
        int p = p0 + wn * 32 + ni * 16 + l15;
        out[((size_t)b * 512 + row) * 2048 + p] = acc[mi][ni][r] + bo[row];
      }
    }
  }
}

// ---------------------------------------------------------------------------
extern "C" void kernel_launch(void* const* d_in, const int* in_sizes, int n_in,
                              void* d_out, int out_size, void* d_ws, size_t ws_size,
                              hipStream_t stream) {
  (void)in_sizes; (void)n_in; (void)out_size; (void)ws_size;
  const float* Q  = (const float*)d_in[0];
  const float* Wq = (const float*)d_in[1];
  const float* bq = (const float*)d_in[2];
  const float* Wk = (const float*)d_in[3];
  const float* bk = (const float*)d_in[4];
  const float* Wv = (const float*)d_in[5];
  const float* bv = (const float*)d_in[6];
  const float* Wo = (const float*)d_in[7];
  const float* bo = (const float*)d_in[8];
  float* out = (float*)d_out;

  char* ws = (char*)d_ws;
  bf16*  Wf    = (bf16*)(ws + 0);          // 1536*512*2  = 1572864
  bf16*  Wor   = (bf16*)(ws + 1572864);    // 512*512*2   = 524288
  float* biasf = (float*)(ws + 2097152);   // 1536*4      = 6144
  bf16*  Qt    = (bf16*)(ws + 2103296);    // 2*2048*512*2 = 4194304
  bf16*  qp    = (bf16*)(ws + 6297600);    // 4194304
  bf16*  kp    = (bf16*)(ws + 10491904);   // 4194304
  bf16*  vn    = (bf16*)(ws + 14686208);   // 4194304
  bf16*  oh    = (bf16*)(ws + 18880512);   // 4194304  (ends 23074816)
  bf16*  Opart = (bf16*)(ws + 23074816);   // 2*16*2048*64*2 = 8388608
  float* mbuf  = (float*)(ws + 31463424);  // 2*16*2048*4 = 262144
  float* lbuf  = (float*)(ws + 31725568);  // 262144 (ends ~32.0 MB)

  prep_w<<<dim3(2048), dim3(256), 0, stream>>>(Wq, bq, Wk, bk, Wv, bv, Wo,
                                               Wf, biasf, Wor);
  prep_qt<<<dim3(32, 8, 2), dim3(256), 0, stream>>>(Q, Qt);
  qkv_gemm<<<dim3(12, 32, 2), dim3(256), 0, stream>>>(Wf, Qt, biasf, qp, kp, vn);
  attn_k<<<dim3(16, 16, 2), dim3(256), 0, stream>>>(qp, kp, vn, Opart, mbuf, lbuf);
  combine<<<dim3(512), dim3(256), 0, stream>>>(Opart, mbuf, lbuf, oh);
  out_gemm<<<dim3(4, 32, 2), dim3(256), 0, stream>>>(Wor, oh, bo, out);
}

// Round 8
// 86.344 us; speedup vs baseline: 1.0169x; 1.0169x over previous
//
#include <hip/hip_runtime.h>

#define DEV __device__ __forceinline__

typedef __bf16 bf16;
typedef __bf16 bf16x8 __attribute__((ext_vector_type(8)));
typedef __bf16 bf16x4 __attribute__((ext_vector_type(4)));
typedef float f32x4 __attribute__((ext_vector_type(4)));

#define B_ 2
#define D_ 512
#define N_ 2048
#define H_ 8
#define MD_ 64
// 1/sqrt(512) * log2(e): scores pre-scaled so softmax uses exp2 directly
#define SCALE_F (0.04419417382415922f * 1.4426950408889634f)

DEV void gload_lds16(const void* g, void* l) {
  __builtin_amdgcn_global_load_lds(
      (const __attribute__((address_space(1))) void*)g,
      (__attribute__((address_space(3))) void*)l, 16, 0, 0);
}

DEV f32x4 mfma16(bf16x8 a, bf16x8 b, f32x4 c) {
  return __builtin_amdgcn_mfma_f32_16x16x32_bf16(a, b, c, 0, 0, 0);
}

// ---------------------------------------------------------------------------
// prep_w: rows 0..1535 -> Wf bf16 (Wq*SCALE | Wk | Wv), bias_f (bq*SCALE|bk|bv)
//         rows 1536..2047 -> Wo_r[r][h*64+d] = Wo[r][d*8+h]  (bf16)
// ---------------------------------------------------------------------------
__global__ __launch_bounds__(256) void prep_w(
    const float* __restrict__ Wq, const float* __restrict__ bq,
    const float* __restrict__ Wk, const float* __restrict__ bk,
    const float* __restrict__ Wv, const float* __restrict__ bv,
    const float* __restrict__ Wo,
    bf16* __restrict__ Wf, float* __restrict__ biasf, bf16* __restrict__ Wor) {
  int row = blockIdx.x;
  int t = threadIdx.x;
  if (row < 1536) {
    const float* src;
    float scale = 1.0f;
    if (row < 512)       { src = Wq + (size_t)row * 512; scale = SCALE_F; }
    else if (row < 1024) { src = Wk + (size_t)(row - 512) * 512; }
    else                 { src = Wv + (size_t)(row - 1024) * 512; }
    for (int c = t; c < 512; c += 256)
      Wf[(size_t)row * 512 + c] = (bf16)(src[c] * scale);
    if (t == 0) {
      float bb;
      if (row < 512)       bb = bq[row] * SCALE_F;
      else if (row < 1024) bb = bk[row - 512];
      else                 bb = bv[row - 1024];
      biasf[row] = bb;
    }
  } else {
    int r = row - 1536;
    for (int c2 = t; c2 < 512; c2 += 256) {
      int hh = c2 >> 6, dd = c2 & 63;
      Wor[(size_t)r * 512 + c2] = (bf16)Wo[(size_t)r * 512 + dd * 8 + hh];
    }
  }
}

// ---------------------------------------------------------------------------
// prep_qt: Qt[b][n][c] = bf16(Q[b][c][n])   (64x64 tiles through LDS)
// grid (N/64, D/64, B), block 256
// ---------------------------------------------------------------------------
__global__ __launch_bounds__(256) void prep_qt(const float* __restrict__ Q,
                                               bf16* __restrict__ Qt) {
  __shared__ float tile[64][65];
  int b = blockIdx.z;
  int d0 = blockIdx.y * 64;
  int n0 = blockIdx.x * 64;
  int t = threadIdx.x;
  int r = t >> 2, cw = t & 3;

  const float* src = Q + ((size_t)(b * 512 + d0 + r)) * 2048 + n0 + cw * 16;
#pragma unroll
  for (int e4 = 0; e4 < 4; ++e4) {
    float4 v = *(const float4*)(src + e4 * 4);
    tile[r][cw * 16 + e4 * 4 + 0] = v.x;
    tile[r][cw * 16 + e4 * 4 + 1] = v.y;
    tile[r][cw * 16 + e4 * 4 + 2] = v.z;
    tile[r][cw * 16 + e4 * 4 + 3] = v.w;
  }
  __syncthreads();
  bf16x8 o0{}, o1{};
#pragma unroll
  for (int e = 0; e < 8; ++e) {
    o0[e] = (bf16)tile[cw * 16 + e][r];
    o1[e] = (bf16)tile[cw * 16 + 8 + e][r];
  }
  bf16* dst = Qt + ((size_t)(b * 2048 + n0 + r)) * 512 + d0 + cw * 16;
  *(bf16x8*)dst = o0;
  *((bf16x8*)dst + 1) = o1;
}

// ---------------------------------------------------------------------------
// qkv_gemm v3: 128x64 tiles, double-buffered LDS, 1 barrier per K-step.
// grid (12, 32, 2) = 768 blocks = 3/CU even. 4 waves 2x2, BK=32.
// C[c][p] = sum_k Wf[c][k] * Qt[b][p][k] + bias[c]
// Epilogue: c<512 -> qp[b][h][p][d]; c<1024 -> kp; else vn[b][c][p]
// ---------------------------------------------------------------------------
__global__ __launch_bounds__(256) void qkv_gemm(
    const bf16* __restrict__ Wf, const bf16* __restrict__ Qt,
    const float* __restrict__ biasf,
    bf16* __restrict__ qp, bf16* __restrict__ kp, bf16* __restrict__ vn) {
  __shared__ bf16 Al[2][128 * 32];
  __shared__ bf16 Bl[2][64 * 32];
  int b = blockIdx.z;
  int c0 = blockIdx.x * 128;
  int p0 = blockIdx.y * 64;
  int tid = threadIdx.x, w = tid >> 6, lane = tid & 63;
  int wm = w >> 1, wn = w & 1;
  int g = lane >> 4, l15 = lane & 15;

  const bf16* Abase = Wf + (size_t)c0 * 512;
  const bf16* Bbase = Qt + ((size_t)b * 2048 + p0) * 512;

  int arow0 = lane >> 2;           // 0..15 within a 16-row group
  int ach = lane & 3;

  f32x4 acc[4][2] = {};

  // prologue: stage ks=0 into buf 0
#pragma unroll
  for (int i = 0; i < 2; ++i)
    gload_lds16(Abase + (size_t)(w * 32 + i * 16 + arow0) * 512 + ach * 8,
                Al[0] + (w * 32 + i * 16) * 32);
  gload_lds16(Bbase + (size_t)(w * 16 + arow0) * 512 + ach * 8,
              Bl[0] + w * 16 * 32);
  __syncthreads();

  for (int ks = 0; ks < 16; ++ks) {
    int cur = ks & 1, nxt = cur ^ 1;
    if (ks < 15) {
      int k0 = (ks + 1) * 32;
#pragma unroll
      for (int i = 0; i < 2; ++i)
        gload_lds16(Abase + (size_t)(w * 32 + i * 16 + arow0) * 512 + k0 + ach * 8,
                    Al[nxt] + (w * 32 + i * 16) * 32);
      gload_lds16(Bbase + (size_t)(w * 16 + arow0) * 512 + k0 + ach * 8,
                  Bl[nxt] + w * 16 * 32);
    }
    bf16x8 a[4], bb[2];
#pragma unroll
    for (int mi = 0; mi < 4; ++mi)
      a[mi] = *(const bf16x8*)(Al[cur] + (wm * 64 + mi * 16 + l15) * 32 + g * 8);
#pragma unroll
    for (int ni = 0; ni < 2; ++ni)
      bb[ni] = *(const bf16x8*)(Bl[cur] + (wn * 32 + ni * 16 + l15) * 32 + g * 8);
#pragma unroll
    for (int mi = 0; mi < 4; ++mi)
#pragma unroll
      for (int ni = 0; ni < 2; ++ni)
        acc[mi][ni] = mfma16(a[mi], bb[ni], acc[mi][ni]);
    __syncthreads();
  }

#pragma unroll
  for (int mi = 0; mi < 4; ++mi) {
#pragma unroll
    for (int ni = 0; ni < 2; ++ni) {
#pragma unroll
      for (int r = 0; r < 4; ++r) {
        int row = c0 + wm * 64 + mi * 16 + g * 4 + r;
        int p = p0 + wn * 32 + ni * 16 + l15;
        float val = acc[mi][ni][r] + biasf[row];
        bf16 hv = (bf16)val;
        if (row < 512) {
          int c = row;
          qp[(((size_t)b * 8 + (c & 7)) * 2048 + p) * 64 + (c >> 3)] = hv;
        } else if (row < 1024) {
          int c = row - 512;
          kp[(((size_t)b * 8 + (c & 7)) * 2048 + p) * 64 + (c >> 3)] = hv;
        } else {
          int c = row - 1024;
          vn[((size_t)b * 512 + c) * 2048 + p] = hv;
        }
      }
    }
  }
}

// ---------------------------------------------------------------------------
// attn_k v8: QBLK=256, 8 waves x 32 q-rows (two 16-row groups/wave): each
// staged K/V b128 read feeds TWO row-groups (halved LDS reads per work) AT
// 16 waves/CU (grid (8, 16, NS) with NS=4 -> 512 blocks = 2 blocks/CU).
// TS = 32/NS KV steps of 64 per block. Swapped QK^T softmax; K/V dbuf,
// 1 barrier/step, setprio. LDS: 2*8(K)+2*8(V)+32(Ps) = 64KB.
// Writes unnormalized O-partial (bf16) + per-row m,l (f32, log2 domain).
// ---------------------------------------------------------------------------
__global__ __launch_bounds__(512, 4) void attn_k(
    const bf16* __restrict__ qp, const bf16* __restrict__ kp,
    const bf16* __restrict__ vn, bf16* __restrict__ Op,
    float* __restrict__ mbuf, float* __restrict__ lbuf, int TS) {
  __shared__ bf16 Ks[2][64 * 64];
  __shared__ bf16 Vs[2][64 * 64];
  __shared__ bf16 Ps[256 * 64];
  int q0 = blockIdx.x * 256;
  int bh = blockIdx.y;            // b*8 + h
  int z = blockIdx.z;             // kv split
  int b = bh >> 3, h = bh & 7;
  int tid = threadIdx.x, w = tid >> 6, lane = tid & 63;
  int g = lane >> 4, l15 = lane & 15;

  // Q B-fragments for both row groups (reused all TS steps)
  bf16x8 qreg[2][2];
#pragma unroll
  for (int rg = 0; rg < 2; ++rg)
#pragma unroll
    for (int ks2 = 0; ks2 < 2; ++ks2)
      qreg[rg][ks2] = *(const bf16x8*)(
          qp + ((size_t)bh * 2048 + q0 + w * 32 + rg * 16 + l15) * 64 +
          ks2 * 32 + g * 8);

  // staging: 512 threads x 16B = 8KB = one full 64x64 tile per issue.
  // wave w writes rows w*8..w*8+7 (linear dest); swizzled global source.
  int krow = tid >> 3;            // 0..63
  int kch = (tid & 7) ^ (krow & 7);

  const bf16* Kall = kp + (size_t)bh * 2048 * 64 + (size_t)z * TS * 4096;
  const bf16* Vall = vn + ((size_t)(b * 512 + h)) * 2048 + (size_t)z * TS * 64;

  // stage K/V local step 0 into buffer 0
  gload_lds16(Kall + (size_t)krow * 64 + kch * 8, Ks[0] + w * 512);
  gload_lds16(Vall + (size_t)krow * 16384 + kch * 8, Vs[0] + w * 512);

  f32x4 oacc[2][4] = {};
  float mrow[2] = {-1e30f, -1e30f}, rs[2] = {0.0f, 0.0f};

  __syncthreads();  // step-0 staging drained (vmcnt(0) inside)

  for (int t = 0; t < TS; ++t) {
    int cur = t & 1, nxt = cur ^ 1;
    int tn = (t < TS - 1) ? t + 1 : t;  // clamp (redundant last prefetch)

    // issue next-step staging (lands during compute; drained at loop-end sync)
    gload_lds16(Kall + (size_t)tn * 4096 + (size_t)krow * 64 + kch * 8,
                Ks[nxt] + w * 512);
    gload_lds16(Vall + (size_t)tn * 64 + (size_t)krow * 16384 + kch * 8,
                Vs[nxt] + w * 512);

    // S^T = K Q^T for both groups; each kb read feeds 2 MFMA
    f32x4 st[2][4] = {};
    __builtin_amdgcn_s_setprio(1);
#pragma unroll
    for (int ks2 = 0; ks2 < 2; ++ks2) {
#pragma unroll
      for (int jt = 0; jt < 4; ++jt) {
        int jrow = jt * 16 + l15;
        bf16x8 kb = *(const bf16x8*)(Ks[cur] + jrow * 64 +
                                     (((ks2 * 4 + g) ^ (jrow & 7)) << 3));
        st[0][jt] = mfma16(kb, qreg[0][ks2], st[0][jt]);
        st[1][jt] = mfma16(kb, qreg[1][ks2], st[1][jt]);
      }
    }
    __builtin_amdgcn_s_setprio(0);

    // per-lane row max per group (15 fmax) + 2 shfl_xor across g-copies
    float rm[2];
#pragma unroll
    for (int rg = 0; rg < 2; ++rg) {
      float m0 = st[rg][0][0];
#pragma unroll
      for (int jt = 0; jt < 4; ++jt)
#pragma unroll
        for (int i = 0; i < 4; ++i) m0 = fmaxf(m0, st[rg][jt][i]);
      m0 = fmaxf(m0, __shfl_xor(m0, 16));
      m0 = fmaxf(m0, __shfl_xor(m0, 32));
      rm[rg] = m0;
    }

    if (__any(fmaxf(rm[0] - mrow[0], rm[1] - mrow[1]) > 8.0f)) {
#pragma unroll
      for (int rg = 0; rg < 2; ++rg) {
        float nm = fmaxf(mrow[rg], rm[rg]);
        float esc = __builtin_amdgcn_exp2f(mrow[rg] - nm);
        mrow[rg] = nm;
        rs[rg] *= esc;
#pragma unroll
        for (int r = 0; r < 4; ++r) {
          float er = __shfl(esc, g * 4 + r, 64);
#pragma unroll
          for (int dt = 0; dt < 4; ++dt) oacc[rg][dt][r] *= er;
        }
      }
    }

    // P = exp2(S - m): 4 consecutive j per jt -> ds_write_b64 per (rg,jt)
#pragma unroll
    for (int rg = 0; rg < 2; ++rg) {
      int prow = w * 32 + rg * 16 + l15;
#pragma unroll
      for (int jt = 0; jt < 4; ++jt) {
        bf16x4 pk;
#pragma unroll
        for (int i = 0; i < 4; ++i) {
          float pv = __builtin_amdgcn_exp2f(st[rg][jt][i] - mrow[rg]);
          rs[rg] += pv;
          pk[i] = (bf16)pv;
        }
        *(bf16x4*)(Ps + prow * 64 + ((jt * 16 + g * 4) ^ ((prow & 7) << 3))) = pk;
      }
    }

    // O += P V  (each vb read feeds 2 MFMA; Ps rows wave-private)
    __builtin_amdgcn_s_setprio(1);
#pragma unroll
    for (int ks2 = 0; ks2 < 2; ++ks2) {
      int r0w = w * 32 + l15;
      int r1w = w * 32 + 16 + l15;
      bf16x8 pa0 = *(const bf16x8*)(Ps + r0w * 64 +
                                    (((ks2 * 4 + g) ^ (r0w & 7)) << 3));
      bf16x8 pa1 = *(const bf16x8*)(Ps + r1w * 64 +
                                    (((ks2 * 4 + g) ^ (r1w & 7)) << 3));
#pragma unroll
      for (int dt = 0; dt < 4; ++dt) {
        int drow = dt * 16 + l15;
        bf16x8 vb = *(const bf16x8*)(Vs[cur] + drow * 64 +
                                     (((ks2 * 4 + g) ^ (drow & 7)) << 3));
        oacc[0][dt] = mfma16(pa0, vb, oacc[0][dt]);
        oacc[1][dt] = mfma16(pa1, vb, oacc[1][dt]);
      }
    }
    __builtin_amdgcn_s_setprio(0);

    __syncthreads();  // drains next-step staging + releases buf[cur]
  }

  // full row sums (combine the 4 g-copies)
#pragma unroll
  for (int rg = 0; rg < 2; ++rg) {
    rs[rg] += __shfl_xor(rs[rg], 16);
    rs[rg] += __shfl_xor(rs[rg], 32);
  }

  // epilogue: UNNORMALIZED partial O (bf16) + m,l per row
  size_t zb = (size_t)(z * 16 + bh) * 2048 + q0;
#pragma unroll
  for (int rg = 0; rg < 2; ++rg) {
#pragma unroll
    for (int dt = 0; dt < 4; ++dt) {
#pragma unroll
      for (int r = 0; r < 4; ++r) {
        int i = w * 32 + rg * 16 + g * 4 + r;
        Op[(zb + i) * 64 + dt * 16 + l15] = (bf16)oacc[rg][dt][r];
      }
    }
  }
  if (lane < 16) {  // g==0: one lane per q-row per group
#pragma unroll
    for (int rg = 0; rg < 2; ++rg) {
      int i = w * 32 + rg * 16 + l15;
      mbuf[zb + i] = mrow[rg];
      lbuf[zb + i] = rs[rg];
    }
  }
}

// ---------------------------------------------------------------------------
// combine v2: oh[row][d] = sum_z wz*O_z / sum_z wz*l_z, wz = 2^(m_z - M).
// Runtime NS; oh may ALIAS Op[z=0] (each thread reads only its own (row,dc)
// slice from all z, then writes the same slice -> race-free in-place).
// 131072 threads: thread = (row, 16-d chunk). grid 512, block 256.
// ---------------------------------------------------------------------------
__global__ __launch_bounds__(256) void combine(
    const bf16* __restrict__ Op, const float* __restrict__ mbuf,
    const float* __restrict__ lbuf, bf16* __restrict__ oh, int NS) {
  int idx = blockIdx.x * 256 + threadIdx.x;
  int row = idx >> 2;             // bh*2048 + n
  int dc = (idx & 3) * 16;

  float M = -1e30f;
  for (int z = 0; z < NS; ++z) M = fmaxf(M, mbuf[(size_t)z * 32768 + row]);

  float L = 0.0f;
  float acc[16];
#pragma unroll
  for (int e = 0; e < 16; ++e) acc[e] = 0.0f;

  for (int z = 0; z < NS; ++z) {
    float wz = __builtin_amdgcn_exp2f(mbuf[(size_t)z * 32768 + row] - M);
    L += wz * lbuf[(size_t)z * 32768 + row];
    const bf16x8* p = (const bf16x8*)(Op + ((size_t)z * 32768 + row) * 64 + dc);
#pragma unroll
    for (int v = 0; v < 2; ++v) {
      bf16x8 x = p[v];
#pragma unroll
      for (int e = 0; e < 8; ++e) acc[v * 8 + e] += wz * (float)x[e];
    }
  }
  float invL = 1.0f / L;
  bf16x8* po = (bf16x8*)(oh + (size_t)row * 64 + dc);
#pragma unroll
  for (int v = 0; v < 2; ++v) {
    bf16x8 o;
#pragma unroll
    for (int e = 0; e < 8; ++e) o[e] = (bf16)(acc[v * 8 + e] * invL);
    po[v] = o;
  }
}

// ---------------------------------------------------------------------------
// out_gemm v3: 128x64 tiles, double-buffered LDS, 1 barrier per K-step.
// grid (4, 32, 2) = 256 blocks. 4 waves 2x2, BK=32.
// out[b][r][p] = sum_k Wor[r][k] * oh_as_B[p][k] + bo[r]   (fp32 out)
// ---------------------------------------------------------------------------
__global__ __launch_bounds__(256) void out_gemm(
    const bf16* __restrict__ Wor, const bf16* __restrict__ oh,
    const float* __restrict__ bo, float* __restrict__ out) {
  __shared__ bf16 Al[2][128 * 32];
  __shared__ bf16 Bl[2][64 * 32];
  int b = blockIdx.z;
  int r0 = blockIdx.x * 128;
  int p0 = blockIdx.y * 64;
  int tid = threadIdx.x, w = tid >> 6, lane = tid & 63;
  int wm = w >> 1, wn = w & 1;
  int g = lane >> 4, l15 = lane & 15;

  const bf16* Abase = Wor + (size_t)r0 * 512;
  const bf16* Bhead = oh + (size_t)b * 8 * 2048 * 64 + (size_t)p0 * 64;

  int arow0 = lane >> 2;
  int ach = lane & 3;

  f32x4 acc[4][2] = {};

  // k-step ks covers k0 = ks*32: B rows live at oh[b][k0>>6][p][k0&63 ..]
#pragma unroll
  for (int i = 0; i < 2; ++i)
    gload_lds16(Abase + (size_t)(w * 32 + i * 16 + arow0) * 512 + ach * 8,
                Al[0] + (w * 32 + i * 16) * 32);
  gload_lds16(Bhead + (size_t)(w * 16 + arow0) * 64 + ach * 8,
              Bl[0] + w * 16 * 32);
  __syncthreads();

  for (int ks = 0; ks < 16; ++ks) {
    int cur = ks & 1, nxt = cur ^ 1;
    if (ks < 15) {
      int k0 = (ks + 1) * 32;
      const bf16* Bbase = Bhead + (size_t)(k0 >> 6) * 2048 * 64 + (k0 & 63);
#pragma unroll
      for (int i = 0; i < 2; ++i)
        gload_lds16(Abase + (size_t)(w * 32 + i * 16 + arow0) * 512 + k0 + ach * 8,
                    Al[nxt] + (w * 32 + i * 16) * 32);
      gload_lds16(Bbase + (size_t)(w * 16 + arow0) * 64 + ach * 8,
                  Bl[nxt] + w * 16 * 32);
    }
    bf16x8 a[4], bb[2];
#pragma unroll
    for (int mi = 0; mi < 4; ++mi)
      a[mi] = *(const bf16x8*)(Al[cur] + (wm * 64 + mi * 16 + l15) * 32 + g * 8);
#pragma unroll
    for (int ni = 0; ni < 2; ++ni)
      bb[ni] = *(const bf16x8*)(Bl[cur] + (wn * 32 + ni * 16 + l15) * 32 + g * 8);
#pragma unroll
    for (int mi = 0; mi < 4; ++mi)
#pragma unroll
      for (int ni = 0; ni < 2; ++ni)
        acc[mi][ni] = mfma16(a[mi], bb[ni], acc[mi][ni]);
    __syncthreads();
  }

#pragma unroll
  for (int mi = 0; mi < 4; ++mi) {
#pragma unroll
    for (int ni = 0; ni < 2; ++ni) {
#pragma unroll
      for (int r = 0; r < 4; ++r) {
        int row = r0 + wm * 64 + mi * 16 + g * 4 + r;
        int p = p0 + wn * 32 + ni * 16 + l15;
        out[((size_t)b * 512 + row) * 2048 + p] = acc[mi][ni][r] + bo[row];
      }
    }
  }
}

// ---------------------------------------------------------------------------
extern "C" void kernel_launch(void* const* d_in, const int* in_sizes, int n_in,
                              void* d_out, int out_size, void* d_ws, size_t ws_size,
                              hipStream_t stream) {
  (void)in_sizes; (void)n_in; (void)out_size;
  const float* Q  = (const float*)d_in[0];
  const float* Wq = (const float*)d_in[1];
  const float* bq = (const float*)d_in[2];
  const float* Wk = (const float*)d_in[3];
  const float* bk = (const float*)d_in[4];
  const float* Wv = (const float*)d_in[5];
  const float* bv = (const float*)d_in[6];
  const float* Wo = (const float*)d_in[7];
  const float* bo = (const float*)d_in[8];
  float* out = (float*)d_out;

  char* ws = (char*)d_ws;
  bf16*  Wf    = (bf16*)(ws + 0);          // 1536*512*2  = 1572864
  bf16*  Wor   = (bf16*)(ws + 1572864);    // 512*512*2   = 524288
  float* biasf = (float*)(ws + 2097152);   // 1536*4      = 6144
  bf16*  Qt    = (bf16*)(ws + 2103296);    // 2*2048*512*2 = 4194304
  bf16*  qp    = (bf16*)(ws + 6297600);    // 4194304
  bf16*  kp    = (bf16*)(ws + 10491904);   // 4194304
  bf16*  vn    = (bf16*)(ws + 14686208);   // 4194304 (ends 18880512)

  // KV-split factor: NS=4 needs Opart 16MB + m/l 1MB past 18880512.
  size_t need4 = 18880512ull + 4ull * 4194304 + 2ull * 4ull * 131072;
  int NS = (ws_size >= need4) ? 4 : 2;
  int TS = 32 / NS;

  bf16*  Opart = (bf16*)(ws + 18880512);               // NS * 4194304 bytes
  float* mbuf  = (float*)(ws + 18880512 + (size_t)NS * 4194304);
  float* lbuf  = (float*)(ws + 18880512 + (size_t)NS * 4194304 +
                          (size_t)NS * 131072);
  bf16*  oh    = Opart;  // combine writes in place over z=0 (race-free)

  prep_w<<<dim3(2048), dim3(256), 0, stream>>>(Wq, bq, Wk, bk, Wv, bv, Wo,
                                               Wf, biasf, Wor);
  prep_qt<<<dim3(32, 8, 2), dim3(256), 0, stream>>>(Q, Qt);
  qkv_gemm<<<dim3(12, 32, 2), dim3(256), 0, stream>>>(Wf, Qt, biasf, qp, kp, vn);
  attn_k<<<dim3(8, 16, NS), dim3(512), 0, stream>>>(qp, kp, vn, Opart, mbuf,
                                                    lbuf, TS);
  combine<<<dim3(512), dim3(256), 0, stream>>>(Opart, mbuf, lbuf, oh, NS);
  out_gemm<<<dim3(4, 32, 2), dim3(256), 0, stream>>>(Wor, oh, bo, out);
}

// Round 9
// 83.349 us; speedup vs baseline: 1.0534x; 1.0359x over previous
//
#include <hip/hip_runtime.h>

#define DEV __device__ __forceinline__

typedef __bf16 bf16;
typedef __bf16 bf16x8 __attribute__((ext_vector_type(8)));
typedef __bf16 bf16x4 __attribute__((ext_vector_type(4)));
typedef float f32x4 __attribute__((ext_vector_type(4)));

#define B_ 2
#define D_ 512
#define N_ 2048
#define H_ 8
#define MD_ 64
// 1/sqrt(512) * log2(e): scores pre-scaled so softmax uses exp2 directly
#define SCALE_F (0.04419417382415922f * 1.4426950408889634f)

DEV void gload_lds16(const void* g, void* l) {
  __builtin_amdgcn_global_load_lds(
      (const __attribute__((address_space(1))) void*)g,
      (__attribute__((address_space(3))) void*)l, 16, 0, 0);
}

DEV f32x4 mfma16(bf16x8 a, bf16x8 b, f32x4 c) {
  return __builtin_amdgcn_mfma_f32_16x16x32_bf16(a, b, c, 0, 0, 0);
}

// ---------------------------------------------------------------------------
// prep_w: rows 0..1535 -> Wf bf16 (Wq*SCALE | Wk | Wv), bias_f (bq*SCALE|bk|bv)
//         rows 1536..2047 -> Wo_r[r][h*64+d] = Wo[r][d*8+h]  (bf16)
// ---------------------------------------------------------------------------
__global__ __launch_bounds__(256) void prep_w(
    const float* __restrict__ Wq, const float* __restrict__ bq,
    const float* __restrict__ Wk, const float* __restrict__ bk,
    const float* __restrict__ Wv, const float* __restrict__ bv,
    const float* __restrict__ Wo,
    bf16* __restrict__ Wf, float* __restrict__ biasf, bf16* __restrict__ Wor) {
  int row = blockIdx.x;
  int t = threadIdx.x;
  if (row < 1536) {
    const float* src;
    float scale = 1.0f;
    if (row < 512)       { src = Wq + (size_t)row * 512; scale = SCALE_F; }
    else if (row < 1024) { src = Wk + (size_t)(row - 512) * 512; }
    else                 { src = Wv + (size_t)(row - 1024) * 512; }
    for (int c = t; c < 512; c += 256)
      Wf[(size_t)row * 512 + c] = (bf16)(src[c] * scale);
    if (t == 0) {
      float bb;
      if (row < 512)       bb = bq[row] * SCALE_F;
      else if (row < 1024) bb = bk[row - 512];
      else                 bb = bv[row - 1024];
      biasf[row] = bb;
    }
  } else {
    int r = row - 1536;
    for (int c2 = t; c2 < 512; c2 += 256) {
      int hh = c2 >> 6, dd = c2 & 63;
      Wor[(size_t)r * 512 + c2] = (bf16)Wo[(size_t)r * 512 + dd * 8 + hh];
    }
  }
}

// ---------------------------------------------------------------------------
// prep_qt: Qt[b][n][c] = bf16(Q[b][c][n])   (64x64 tiles through LDS)
// grid (N/64, D/64, B), block 256
// ---------------------------------------------------------------------------
__global__ __launch_bounds__(256) void prep_qt(const float* __restrict__ Q,
                                               bf16* __restrict__ Qt) {
  __shared__ float tile[64][65];
  int b = blockIdx.z;
  int d0 = blockIdx.y * 64;
  int n0 = blockIdx.x * 64;
  int t = threadIdx.x;
  int r = t >> 2, cw = t & 3;

  const float* src = Q + ((size_t)(b * 512 + d0 + r)) * 2048 + n0 + cw * 16;
#pragma unroll
  for (int e4 = 0; e4 < 4; ++e4) {
    float4 v = *(const float4*)(src + e4 * 4);
    tile[r][cw * 16 + e4 * 4 + 0] = v.x;
    tile[r][cw * 16 + e4 * 4 + 1] = v.y;
    tile[r][cw * 16 + e4 * 4 + 2] = v.z;
    tile[r][cw * 16 + e4 * 4 + 3] = v.w;
  }
  __syncthreads();
  bf16x8 o0{}, o1{};
#pragma unroll
  for (int e = 0; e < 8; ++e) {
    o0[e] = (bf16)tile[cw * 16 + e][r];
    o1[e] = (bf16)tile[cw * 16 + 8 + e][r];
  }
  bf16* dst = Qt + ((size_t)(b * 2048 + n0 + r)) * 512 + d0 + cw * 16;
  *(bf16x8*)dst = o0;
  *((bf16x8*)dst + 1) = o1;
}

// ---------------------------------------------------------------------------
// qkv_gemm v2 (R6 form): 128x64 tiles, single-buffer, 2 barriers/K-step.
// grid (12, 32, 2) = 768 blocks = 3/CU even. 4 waves 2x2, BK=32.
// C[c][p] = sum_k Wf[c][k] * Qt[b][p][k] + bias[c]
// Epilogue: c<512 -> qp[b][h][p][d]; c<1024 -> kp; else vn[b][c][p]
// ---------------------------------------------------------------------------
__global__ __launch_bounds__(256) void qkv_gemm(
    const bf16* __restrict__ Wf, const bf16* __restrict__ Qt,
    const float* __restrict__ biasf,
    bf16* __restrict__ qp, bf16* __restrict__ kp, bf16* __restrict__ vn) {
  __shared__ bf16 Al[128 * 32];
  __shared__ bf16 Bl[64 * 32];
  int b = blockIdx.z;
  int c0 = blockIdx.x * 128;
  int p0 = blockIdx.y * 64;
  int tid = threadIdx.x, w = tid >> 6, lane = tid & 63;
  int wm = w >> 1, wn = w & 1;
  int g = lane >> 4, l15 = lane & 15;

  const bf16* Abase = Wf + (size_t)c0 * 512;
  const bf16* Bbase = Qt + ((size_t)b * 2048 + p0) * 512;

  f32x4 acc[4][2] = {};

  for (int ks = 0; ks < 16; ++ks) {
    int k0 = ks * 32;
    __syncthreads();
#pragma unroll
    for (int i = 0; i < 2; ++i) {
      int rowl = w * 32 + i * 16 + (lane >> 2);
      gload_lds16(Abase + (size_t)rowl * 512 + k0 + (lane & 3) * 8,
                  Al + (w * 32 + i * 16) * 32);
    }
    {
      int browl = w * 16 + (lane >> 2);
      gload_lds16(Bbase + (size_t)browl * 512 + k0 + (lane & 3) * 8,
                  Bl + w * 16 * 32);
    }
    __syncthreads();
    bf16x8 a[4], bb[2];
#pragma unroll
    for (int mi = 0; mi < 4; ++mi)
      a[mi] = *(const bf16x8*)(Al + (wm * 64 + mi * 16 + l15) * 32 + g * 8);
#pragma unroll
    for (int ni = 0; ni < 2; ++ni)
      bb[ni] = *(const bf16x8*)(Bl + (wn * 32 + ni * 16 + l15) * 32 + g * 8);
#pragma unroll
    for (int mi = 0; mi < 4; ++mi)
#pragma unroll
      for (int ni = 0; ni < 2; ++ni)
        acc[mi][ni] = mfma16(a[mi], bb[ni], acc[mi][ni]);
  }

#pragma unroll
  for (int mi = 0; mi < 4; ++mi) {
#pragma unroll
    for (int ni = 0; ni < 2; ++ni) {
#pragma unroll
      for (int r = 0; r < 4; ++r) {
        int row = c0 + wm * 64 + mi * 16 + g * 4 + r;
        int p = p0 + wn * 32 + ni * 16 + l15;
        float val = acc[mi][ni][r] + biasf[row];
        bf16 hv = (bf16)val;
        if (row < 512) {
          int c = row;
          qp[(((size_t)b * 8 + (c & 7)) * 2048 + p) * 64 + (c >> 3)] = hv;
        } else if (row < 1024) {
          int c = row - 512;
          kp[(((size_t)b * 8 + (c & 7)) * 2048 + p) * 64 + (c >> 3)] = hv;
        } else {
          int c = row - 1024;
          vn[((size_t)b * 512 + c) * 2048 + p] = hv;
        }
      }
    }
  }
}

// ---------------------------------------------------------------------------
// attn_k v8 (unchanged from R8): QBLK=256, 8 waves x 32 q-rows.
// grid (8, 16, NS); TS = 32/NS steps. LDS 64KB -> 2 blocks/CU = 16 waves/CU.
// ---------------------------------------------------------------------------
__global__ __launch_bounds__(512, 4) void attn_k(
    const bf16* __restrict__ qp, const bf16* __restrict__ kp,
    const bf16* __restrict__ vn, bf16* __restrict__ Op,
    float* __restrict__ mbuf, float* __restrict__ lbuf, int TS) {
  __shared__ bf16 Ks[2][64 * 64];
  __shared__ bf16 Vs[2][64 * 64];
  __shared__ bf16 Ps[256 * 64];
  int q0 = blockIdx.x * 256;
  int bh = blockIdx.y;            // b*8 + h
  int z = blockIdx.z;             // kv split
  int b = bh >> 3, h = bh & 7;
  int tid = threadIdx.x, w = tid >> 6, lane = tid & 63;
  int g = lane >> 4, l15 = lane & 15;

  // Q B-fragments for both row groups (reused all TS steps)
  bf16x8 qreg[2][2];
#pragma unroll
  for (int rg = 0; rg < 2; ++rg)
#pragma unroll
    for (int ks2 = 0; ks2 < 2; ++ks2)
      qreg[rg][ks2] = *(const bf16x8*)(
          qp + ((size_t)bh * 2048 + q0 + w * 32 + rg * 16 + l15) * 64 +
          ks2 * 32 + g * 8);

  // staging: 512 threads x 16B = 8KB = one full 64x64 tile per issue.
  int krow = tid >> 3;            // 0..63
  int kch = (tid & 7) ^ (krow & 7);

  const bf16* Kall = kp + (size_t)bh * 2048 * 64 + (size_t)z * TS * 4096;
  const bf16* Vall = vn + ((size_t)(b * 512 + h)) * 2048 + (size_t)z * TS * 64;

  // stage K/V local step 0 into buffer 0
  gload_lds16(Kall + (size_t)krow * 64 + kch * 8, Ks[0] + w * 512);
  gload_lds16(Vall + (size_t)krow * 16384 + kch * 8, Vs[0] + w * 512);

  f32x4 oacc[2][4] = {};
  float mrow[2] = {-1e30f, -1e30f}, rs[2] = {0.0f, 0.0f};

  __syncthreads();  // step-0 staging drained (vmcnt(0) inside)

  for (int t = 0; t < TS; ++t) {
    int cur = t & 1, nxt = cur ^ 1;
    int tn = (t < TS - 1) ? t + 1 : t;  // clamp (redundant last prefetch)

    // issue next-step staging (lands during compute; drained at loop-end sync)
    gload_lds16(Kall + (size_t)tn * 4096 + (size_t)krow * 64 + kch * 8,
                Ks[nxt] + w * 512);
    gload_lds16(Vall + (size_t)tn * 64 + (size_t)krow * 16384 + kch * 8,
                Vs[nxt] + w * 512);

    // S^T = K Q^T for both groups; each kb read feeds 2 MFMA
    f32x4 st[2][4] = {};
    __builtin_amdgcn_s_setprio(1);
#pragma unroll
    for (int ks2 = 0; ks2 < 2; ++ks2) {
#pragma unroll
      for (int jt = 0; jt < 4; ++jt) {
        int jrow = jt * 16 + l15;
        bf16x8 kb = *(const bf16x8*)(Ks[cur] + jrow * 64 +
                                     (((ks2 * 4 + g) ^ (jrow & 7)) << 3));
        st[0][jt] = mfma16(kb, qreg[0][ks2], st[0][jt]);
        st[1][jt] = mfma16(kb, qreg[1][ks2], st[1][jt]);
      }
    }
    __builtin_amdgcn_s_setprio(0);

    // per-lane row max per group (15 fmax) + 2 shfl_xor across g-copies
    float rm[2];
#pragma unroll
    for (int rg = 0; rg < 2; ++rg) {
      float m0 = st[rg][0][0];
#pragma unroll
      for (int jt = 0; jt < 4; ++jt)
#pragma unroll
        for (int i = 0; i < 4; ++i) m0 = fmaxf(m0, st[rg][jt][i]);
      m0 = fmaxf(m0, __shfl_xor(m0, 16));
      m0 = fmaxf(m0, __shfl_xor(m0, 32));
      rm[rg] = m0;
    }

    if (__any(fmaxf(rm[0] - mrow[0], rm[1] - mrow[1]) > 8.0f)) {
#pragma unroll
      for (int rg = 0; rg < 2; ++rg) {
        float nm = fmaxf(mrow[rg], rm[rg]);
        float esc = __builtin_amdgcn_exp2f(mrow[rg] - nm);
        mrow[rg] = nm;
        rs[rg] *= esc;
#pragma unroll
        for (int r = 0; r < 4; ++r) {
          float er = __shfl(esc, g * 4 + r, 64);
#pragma unroll
          for (int dt = 0; dt < 4; ++dt) oacc[rg][dt][r] *= er;
        }
      }
    }

    // P = exp2(S - m): 4 consecutive j per jt -> ds_write_b64 per (rg,jt)
#pragma unroll
    for (int rg = 0; rg < 2; ++rg) {
      int prow = w * 32 + rg * 16 + l15;
#pragma unroll
      for (int jt = 0; jt < 4; ++jt) {
        bf16x4 pk;
#pragma unroll
        for (int i = 0; i < 4; ++i) {
          float pv = __builtin_amdgcn_exp2f(st[rg][jt][i] - mrow[rg]);
          rs[rg] += pv;
          pk[i] = (bf16)pv;
        }
        *(bf16x4*)(Ps + prow * 64 + ((jt * 16 + g * 4) ^ ((prow & 7) << 3))) = pk;
      }
    }

    // O += P V  (each vb read feeds 2 MFMA; Ps rows wave-private)
    __builtin_amdgcn_s_setprio(1);
#pragma unroll
    for (int ks2 = 0; ks2 < 2; ++ks2) {
      int r0w = w * 32 + l15;
      int r1w = w * 32 + 16 + l15;
      bf16x8 pa0 = *(const bf16x8*)(Ps + r0w * 64 +
                                    (((ks2 * 4 + g) ^ (r0w & 7)) << 3));
      bf16x8 pa1 = *(const bf16x8*)(Ps + r1w * 64 +
                                    (((ks2 * 4 + g) ^ (r1w & 7)) << 3));
#pragma unroll
      for (int dt = 0; dt < 4; ++dt) {
        int drow = dt * 16 + l15;
        bf16x8 vb = *(const bf16x8*)(Vs[cur] + drow * 64 +
                                     (((ks2 * 4 + g) ^ (drow & 7)) << 3));
        oacc[0][dt] = mfma16(pa0, vb, oacc[0][dt]);
        oacc[1][dt] = mfma16(pa1, vb, oacc[1][dt]);
      }
    }
    __builtin_amdgcn_s_setprio(0);

    __syncthreads();  // drains next-step staging + releases buf[cur]
  }

  // full row sums (combine the 4 g-copies)
#pragma unroll
  for (int rg = 0; rg < 2; ++rg) {
    rs[rg] += __shfl_xor(rs[rg], 16);
    rs[rg] += __shfl_xor(rs[rg], 32);
  }

  // epilogue: UNNORMALIZED partial O (bf16) + m,l per row
  size_t zb = (size_t)(z * 16 + bh) * 2048 + q0;
#pragma unroll
  for (int rg = 0; rg < 2; ++rg) {
#pragma unroll
    for (int dt = 0; dt < 4; ++dt) {
#pragma unroll
      for (int r = 0; r < 4; ++r) {
        int i = w * 32 + rg * 16 + g * 4 + r;
        Op[(zb + i) * 64 + dt * 16 + l15] = (bf16)oacc[rg][dt][r];
      }
    }
  }
  if (lane < 16) {  // g==0: one lane per q-row per group
#pragma unroll
    for (int rg = 0; rg < 2; ++rg) {
      int i = w * 32 + rg * 16 + l15;
      mbuf[zb + i] = mrow[rg];
      lbuf[zb + i] = rs[rg];
    }
  }
}

// ---------------------------------------------------------------------------
// combine v2: oh[row][d] = sum_z wz*O_z / sum_z wz*l_z, wz = 2^(m_z - M).
// Runtime NS; oh may ALIAS Op[z=0] (each thread reads only its own (row,dc)
// slice from all z, then writes the same slice -> race-free in-place).
// ---------------------------------------------------------------------------
__global__ __launch_bounds__(256) void combine(
    const bf16* __restrict__ Op, const float* __restrict__ mbuf,
    const float* __restrict__ lbuf, bf16* __restrict__ oh, int NS) {
  int idx = blockIdx.x * 256 + threadIdx.x;
  int row = idx >> 2;             // bh*2048 + n
  int dc = (idx & 3) * 16;

  float M = -1e30f;
  for (int z = 0; z < NS; ++z) M = fmaxf(M, mbuf[(size_t)z * 32768 + row]);

  float L = 0.0f;
  float acc[16];
#pragma unroll
  for (int e = 0; e < 16; ++e) acc[e] = 0.0f;

  for (int z = 0; z < NS; ++z) {
    float wz = __builtin_amdgcn_exp2f(mbuf[(size_t)z * 32768 + row] - M);
    L += wz * lbuf[(size_t)z * 32768 + row];
    const bf16x8* p = (const bf16x8*)(Op + ((size_t)z * 32768 + row) * 64 + dc);
#pragma unroll
    for (int v = 0; v < 2; ++v) {
      bf16x8 x = p[v];
#pragma unroll
      for (int e = 0; e < 8; ++e) acc[v * 8 + e] += wz * (float)x[e];
    }
  }
  float invL = 1.0f / L;
  bf16x8* po = (bf16x8*)(oh + (size_t)row * 64 + dc);
#pragma unroll
  for (int v = 0; v < 2; ++v) {
    bf16x8 o;
#pragma unroll
    for (int e = 0; e < 8; ++e) o[e] = (bf16)(acc[v * 8 + e] * invL);
    po[v] = o;
  }
}

// ---------------------------------------------------------------------------
// out_gemm v2 (R6 form): 128x64 tiles, single-buffer, 2 barriers/K-step.
// grid (4, 32, 2) = 256 blocks. 4 waves 2x2, BK=32.
// out[b][r][p] = sum_k Wor[r][k] * oh_as_B[p][k] + bo[r]   (fp32 out)
// ---------------------------------------------------------------------------
__global__ __launch_bounds__(256) void out_gemm(
    const bf16* __restrict__ Wor, const bf16* __restrict__ oh,
    const float* __restrict__ bo, float* __restrict__ out) {
  __shared__ bf16 Al[128 * 32];
  __shared__ bf16 Bl[64 * 32];
  int b = blockIdx.z;
  int r0 = blockIdx.x * 128;
  int p0 = blockIdx.y * 64;
  int tid = threadIdx.x, w = tid >> 6, lane = tid & 63;
  int wm = w >> 1, wn = w & 1;
  int g = lane >> 4, l15 = lane & 15;

  const bf16* Abase = Wor + (size_t)r0 * 512;

  f32x4 acc[4][2] = {};

  for (int ks = 0; ks < 16; ++ks) {
    int k0 = ks * 32;
    int hh = k0 >> 6, d0 = k0 & 63;
    const bf16* Bbase = oh + (((size_t)b * 8 + hh) * 2048 + p0) * 64 + d0;
    __syncthreads();
#pragma unroll
    for (int i = 0; i < 2; ++i) {
      int rowl = w * 32 + i * 16 + (lane >> 2);
      gload_lds16(Abase + (size_t)rowl * 512 + k0 + (lane & 3) * 8,
                  Al + (w * 32 + i * 16) * 32);
    }
    {
      int browl = w * 16 + (lane >> 2);
      gload_lds16(Bbase + (size_t)browl * 64 + (lane & 3) * 8,
                  Bl + w * 16 * 32);
    }
    __syncthreads();
    bf16x8 a[4], bb[2];
#pragma unroll
    for (int mi = 0; mi < 4; ++mi)
      a[mi] = *(const bf16x8*)(Al + (wm * 64 + mi * 16 + l15) * 32 + g * 8);
#pragma unroll
    for (int ni = 0; ni < 2; ++ni)
      bb[ni] = *(const bf16x8*)(Bl + (wn * 32 + ni * 16 + l15) * 32 + g * 8);
#pragma unroll
    for (int mi = 0; mi < 4; ++mi)
#pragma unroll
      for (int ni = 0; ni < 2; ++ni)
        acc[mi][ni] = mfma16(a[mi], bb[ni], acc[mi][ni]);
  }

#pragma unroll
  for (int mi = 0; mi < 4; ++mi) {
#pragma unroll
    for (int ni = 0; ni < 2; ++ni) {
#pragma unroll
      for (int r = 0; r < 4; ++r) {
        int row = r0 + wm * 64 + mi * 16 + g * 4 + r;
        int p = p0 + wn * 32 + ni * 16 + l15;
        out[((size_t)b * 512 + row) * 2048 + p] = acc[mi][ni][r] + bo[row];
      }
    }
  }
}

// ---------------------------------------------------------------------------
extern "C" void kernel_launch(void* const* d_in, const int* in_sizes, int n_in,
                              void* d_out, int out_size, void* d_ws, size_t ws_size,
                              hipStream_t stream) {
  (void)in_sizes; (void)n_in; (void)out_size;
  const float* Q  = (const float*)d_in[0];
  const float* Wq = (const float*)d_in[1];
  const float* bq = (const float*)d_in[2];
  const float* Wk = (const float*)d_in[3];
  const float* bk = (const float*)d_in[4];
  const float* Wv = (const float*)d_in[5];
  const float* bv = (const float*)d_in[6];
  const float* Wo = (const float*)d_in[7];
  const float* bo = (const float*)d_in[8];
  float* out = (float*)d_out;

  char* ws = (char*)d_ws;
  bf16*  Wf    = (bf16*)(ws + 0);          // 1536*512*2  = 1572864
  bf16*  Wor   = (bf16*)(ws + 1572864);    // 512*512*2   = 524288
  float* biasf = (float*)(ws + 2097152);   // 1536*4      = 6144
  bf16*  Qt    = (bf16*)(ws + 2103296);    // 2*2048*512*2 = 4194304
  bf16*  qp    = (bf16*)(ws + 6297600);    // 4194304
  bf16*  kp    = (bf16*)(ws + 10491904);   // 4194304
  bf16*  vn    = (bf16*)(ws + 14686208);   // 4194304 (ends 18880512)

  // KV-split factor: NS=4 needs Opart 16MB + m/l 1MB past 18880512.
  size_t need4 = 18880512ull + 4ull * 4194304 + 2ull * 4ull * 131072;
  int NS = (ws_size >= need4) ? 4 : 2;
  int TS = 32 / NS;

  bf16*  Opart = (bf16*)(ws + 18880512);               // NS * 4194304 bytes
  float* mbuf  = (float*)(ws + 18880512 + (size_t)NS * 4194304);
  float* lbuf  = (float*)(ws + 18880512 + (size_t)NS * 4194304 +
                          (size_t)NS * 131072);
  bf16*  oh    = Opart;  // combine writes in place over z=0 (race-free)

  prep_w<<<dim3(2048), dim3(256), 0, stream>>>(Wq, bq, Wk, bk, Wv, bv, Wo,
                                               Wf, biasf, Wor);
  prep_qt<<<dim3(32, 8, 2), dim3(256), 0, stream>>>(Q, Qt);
  qkv_gemm<<<dim3(12, 32, 2), dim3(256), 0, stream>>>(Wf, Qt, biasf, qp, kp, vn);
  attn_k<<<dim3(8, 16, NS), dim3(512), 0, stream>>>(qp, kp, vn, Opart, mbuf,
                                                    lbuf, TS);
  combine<<<dim3(512), dim3(256), 0, stream>>>(Opart, mbuf, lbuf, oh, NS);
  out_gemm<<<dim3(4, 32, 2), dim3(256), 0, stream>>>(Wor, oh, bo, out);
}

// Round 10
// 80.433 us; speedup vs baseline: 1.0916x; 1.0363x over previous
//
#include <hip/hip_runtime.h>

#define DEV __device__ __forceinline__

typedef __bf16 bf16;
typedef __bf16 bf16x8 __attribute__((ext_vector_type(8)));
typedef __bf16 bf16x4 __attribute__((ext_vector_type(4)));
typedef float f32x4 __attribute__((ext_vector_type(4)));
typedef float f32x16 __attribute__((ext_vector_type(16)));
typedef unsigned int u32x4 __attribute__((ext_vector_type(4)));

// 1/sqrt(512) * log2(e): scores pre-scaled so softmax uses exp2 directly
#define SCALE_F (0.04419417382415922f * 1.4426950408889634f)

DEV void gload_lds16(const void* g, void* l) {
  __builtin_amdgcn_global_load_lds(
      (const __attribute__((address_space(1))) void*)g,
      (__attribute__((address_space(3))) void*)l, 16, 0, 0);
}

DEV f32x4 mfma16(bf16x8 a, bf16x8 b, f32x4 c) {
  return __builtin_amdgcn_mfma_f32_16x16x32_bf16(a, b, c, 0, 0, 0);
}
DEV f32x16 mfma32(bf16x8 a, bf16x8 b, f32x16 c) {
  return __builtin_amdgcn_mfma_f32_32x32x16_bf16(a, b, c, 0, 0, 0);
}

DEV unsigned int pkbf(float a, float b) {
  unsigned short ua = __builtin_bit_cast(unsigned short, (bf16)a);
  unsigned short ub = __builtin_bit_cast(unsigned short, (bf16)b);
  return (unsigned int)ua | ((unsigned int)ub << 16);
}

// ---------------------------------------------------------------------------
// prep: blocks 0..2047 -> weight prep; blocks 2048..2559 -> Q transpose.
// Wf bf16 (Wq*SCALE | Wk | Wv), biasf, Wor[r][h*64+d] = Wo[r][d*8+h].
// Qt[b][n][c] = bf16(Q[b][c][n]).
// ---------------------------------------------------------------------------
__global__ __launch_bounds__(256) void prep(
    const float* __restrict__ Q,
    const float* __restrict__ Wq, const float* __restrict__ bq,
    const float* __restrict__ Wk, const float* __restrict__ bk,
    const float* __restrict__ Wv, const float* __restrict__ bv,
    const float* __restrict__ Wo,
    bf16* __restrict__ Wf, float* __restrict__ biasf, bf16* __restrict__ Wor,
    bf16* __restrict__ Qt) {
  __shared__ float tile[64][65];
  int bid = blockIdx.x;
  int t = threadIdx.x;
  if (bid < 2048) {
    int row = bid;
    if (row < 1536) {
      const float* src;
      float scale = 1.0f;
      if (row < 512)       { src = Wq + (size_t)row * 512; scale = SCALE_F; }
      else if (row < 1024) { src = Wk + (size_t)(row - 512) * 512; }
      else                 { src = Wv + (size_t)(row - 1024) * 512; }
      for (int c = t; c < 512; c += 256)
        Wf[(size_t)row * 512 + c] = (bf16)(src[c] * scale);
      if (t == 0) {
        float bb;
        if (row < 512)       bb = bq[row] * SCALE_F;
        else if (row < 1024) bb = bk[row - 512];
        else                 bb = bv[row - 1024];
        biasf[row] = bb;
      }
    } else {
      int r = row - 1536;
      for (int c2 = t; c2 < 512; c2 += 256) {
        int hh = c2 >> 6, dd = c2 & 63;
        Wor[(size_t)r * 512 + c2] = (bf16)Wo[(size_t)r * 512 + dd * 8 + hh];
      }
    }
  } else {
    int id2 = bid - 2048;
    int n0 = (id2 & 31) * 64;
    int d0 = ((id2 >> 5) & 7) * 64;
    int b = id2 >> 8;
    int r = t >> 2, cw = t & 3;
    const float* src = Q + ((size_t)(b * 512 + d0 + r)) * 2048 + n0 + cw * 16;
#pragma unroll
    for (int e4 = 0; e4 < 4; ++e4) {
      float4 v = *(const float4*)(src + e4 * 4);
      tile[r][cw * 16 + e4 * 4 + 0] = v.x;
      tile[r][cw * 16 + e4 * 4 + 1] = v.y;
      tile[r][cw * 16 + e4 * 4 + 2] = v.z;
      tile[r][cw * 16 + e4 * 4 + 3] = v.w;
    }
    __syncthreads();
    bf16x8 o0{}, o1{};
#pragma unroll
    for (int e = 0; e < 8; ++e) {
      o0[e] = (bf16)tile[cw * 16 + e][r];
      o1[e] = (bf16)tile[cw * 16 + 8 + e][r];
    }
    bf16* dst = Qt + ((size_t)(b * 2048 + n0 + r)) * 512 + d0 + cw * 16;
    *(bf16x8*)dst = o0;
    *((bf16x8*)dst + 1) = o1;
  }
}

// ---------------------------------------------------------------------------
// qkv_gemm (R6/R9 form): 128x64 tiles, single-buffer, 2 barriers/K-step.
// grid (12, 32, 2). Epilogue scatters to qp/kp/vn.
// ---------------------------------------------------------------------------
__global__ __launch_bounds__(256) void qkv_gemm(
    const bf16* __restrict__ Wf, const bf16* __restrict__ Qt,
    const float* __restrict__ biasf,
    bf16* __restrict__ qp, bf16* __restrict__ kp, bf16* __restrict__ vn) {
  __shared__ bf16 Al[128 * 32];
  __shared__ bf16 Bl[64 * 32];
  int b = blockIdx.z;
  int c0 = blockIdx.x * 128;
  int p0 = blockIdx.y * 64;
  int tid = threadIdx.x, w = tid >> 6, lane = tid & 63;
  int wm = w >> 1, wn = w & 1;
  int g = lane >> 4, l15 = lane & 15;

  const bf16* Abase = Wf + (size_t)c0 * 512;
  const bf16* Bbase = Qt + ((size_t)b * 2048 + p0) * 512;

  f32x4 acc[4][2] = {};

  for (int ks = 0; ks < 16; ++ks) {
    int k0 = ks * 32;
    __syncthreads();
#pragma unroll
    for (int i = 0; i < 2; ++i) {
      int rowl = w * 32 + i * 16 + (lane >> 2);
      gload_lds16(Abase + (size_t)rowl * 512 + k0 + (lane & 3) * 8,
                  Al + (w * 32 + i * 16) * 32);
    }
    {
      int browl = w * 16 + (lane >> 2);
      gload_lds16(Bbase + (size_t)browl * 512 + k0 + (lane & 3) * 8,
                  Bl + w * 16 * 32);
    }
    __syncthreads();
    bf16x8 a[4], bb[2];
#pragma unroll
    for (int mi = 0; mi < 4; ++mi)
      a[mi] = *(const bf16x8*)(Al + (wm * 64 + mi * 16 + l15) * 32 + g * 8);
#pragma unroll
    for (int ni = 0; ni < 2; ++ni)
      bb[ni] = *(const bf16x8*)(Bl + (wn * 32 + ni * 16 + l15) * 32 + g * 8);
#pragma unroll
    for (int mi = 0; mi < 4; ++mi)
#pragma unroll
      for (int ni = 0; ni < 2; ++ni)
        acc[mi][ni] = mfma16(a[mi], bb[ni], acc[mi][ni]);
  }

#pragma unroll
  for (int mi = 0; mi < 4; ++mi) {
#pragma unroll
    for (int ni = 0; ni < 2; ++ni) {
#pragma unroll
      for (int r = 0; r < 4; ++r) {
        int row = c0 + wm * 64 + mi * 16 + g * 4 + r;
        int p = p0 + wn * 32 + ni * 16 + l15;
        float val = acc[mi][ni][r] + biasf[row];
        bf16 hv = (bf16)val;
        if (row < 512) {
          int c = row;
          qp[(((size_t)b * 8 + (c & 7)) * 2048 + p) * 64 + (c >> 3)] = hv;
        } else if (row < 1024) {
          int c = row - 512;
          kp[(((size_t)b * 8 + (c & 7)) * 2048 + p) * 64 + (c >> 3)] = hv;
        } else {
          int c = row - 1024;
          vn[((size_t)b * 512 + c) * 2048 + p] = hv;
        }
      }
    }
  }
}

// ---------------------------------------------------------------------------
// attn_k v9: 32x32x16 MFMA, P fully in-register via v_permlane32_swap_b32.
// 8 waves x 32 q-rows (QBLK=256), KV-split NS, grid (8, 16, NS), TS=32/NS.
// Swapped QK^T: q = lane&31 (col), j in regs: j = (r&3)+8*(r>>2)+4*hi.
// PV A-frag (row=q=lane&31, k=j=hi*8+e) built from P runs via 2 permlane
// swaps per k-step -> NO Ps LDS. K/V dbuf (32KB total), 1 barrier/step.
// Writes unnormalized O-partial (bf16) + per-row m,l (f32, log2 domain).
// ---------------------------------------------------------------------------
__global__ __launch_bounds__(512, 4) void attn_k(
    const bf16* __restrict__ qp, const bf16* __restrict__ kp,
    const bf16* __restrict__ vn, bf16* __restrict__ Op,
    float* __restrict__ mbuf, float* __restrict__ lbuf, int TS) {
  __shared__ bf16 Ks[2][64 * 64];
  __shared__ bf16 Vs[2][64 * 64];
  int q0 = blockIdx.x * 256;
  int bh = blockIdx.y;            // b*8 + h
  int z = blockIdx.z;             // kv split
  int b = bh >> 3, h = bh & 7;
  int tid = threadIdx.x, w = tid >> 6, lane = tid & 63;
  int l31 = lane & 31, hi = lane >> 5;

  // Q B-fragments: col=q=l31 (wave's 32 rows), k = kd*16 + hi*8 + e
  bf16x8 qreg[4];
#pragma unroll
  for (int kd = 0; kd < 4; ++kd)
    qreg[kd] = *(const bf16x8*)(
        qp + ((size_t)bh * 2048 + q0 + w * 32 + l31) * 64 + kd * 16 + hi * 8);

  // staging: 512 threads x 16B = 8KB = one full 64x64 tile per issue.
  int krow = tid >> 3;            // 0..63
  int kch = (tid & 7) ^ (krow & 7);

  const bf16* Kall = kp + (size_t)bh * 2048 * 64 + (size_t)z * TS * 4096;
  const bf16* Vall = vn + ((size_t)(b * 512 + h)) * 2048 + (size_t)z * TS * 64;

  gload_lds16(Kall + (size_t)krow * 64 + kch * 8, Ks[0] + w * 512);
  gload_lds16(Vall + (size_t)krow * 16384 + kch * 8, Vs[0] + w * 512);

  f32x16 oacc0 = {}, oacc1 = {};
  float mrow = -1e30f, rs = 0.0f;   // per lane: q-row l31 (hi-half partials)

  __syncthreads();  // step-0 staging drained (vmcnt(0) inside)

  for (int t = 0; t < TS; ++t) {
    int cur = t & 1, nxt = cur ^ 1;
    int tn = (t < TS - 1) ? t + 1 : t;  // clamp (redundant last prefetch)

    gload_lds16(Kall + (size_t)tn * 4096 + (size_t)krow * 64 + kch * 8,
                Ks[nxt] + w * 512);
    gload_lds16(Vall + (size_t)tn * 64 + (size_t)krow * 16384 + kch * 8,
                Vs[nxt] + w * 512);

    // S^T: st[tile][r] = S[q=l31][j = tile*32 + (r&3)+8*(r>>2)+4*hi]
    f32x16 st0 = {}, st1 = {};
    __builtin_amdgcn_s_setprio(1);
#pragma unroll
    for (int kd = 0; kd < 4; ++kd) {
      int sw = ((kd * 2 + hi) ^ (l31 & 7)) << 3;
      bf16x8 kb0 = *(const bf16x8*)(Ks[cur] + l31 * 64 + sw);
      bf16x8 kb1 = *(const bf16x8*)(Ks[cur] + (32 + l31) * 64 + sw);
      st0 = mfma32(kb0, qreg[kd], st0);
      st1 = mfma32(kb1, qreg[kd], st1);
    }
    __builtin_amdgcn_s_setprio(0);

    // row max: 31 in-lane fmax + 1 cross-hi shuffle
    float rm = st0[0];
#pragma unroll
    for (int r = 1; r < 16; ++r) rm = fmaxf(rm, st0[r]);
#pragma unroll
    for (int r = 0; r < 16; ++r) rm = fmaxf(rm, st1[r]);
    rm = fmaxf(rm, __shfl_xor(rm, 32));

    if (__any(rm > mrow + 8.0f)) {  // defer-max guard (step 0 + rare)
      float nm = fmaxf(mrow, rm);
      float esc = __builtin_amdgcn_exp2f(mrow - nm);
      mrow = nm;
      rs *= esc;
#pragma unroll
      for (int r = 0; r < 16; ++r) {
        int ql = (r & 3) + 8 * (r >> 2) + 4 * hi;
        float er = __shfl(esc, ql, 64);  // esc of q-row ql (lane ql holds it)
        oacc0[r] *= er;
        oacc1[r] *= er;
      }
    }

    // P = exp2(S - m) -> bf16 packs -> permlane32_swap -> PV A-frags
    bf16x8 pa[4];
#pragma unroll
    for (int tile = 0; tile < 2; ++tile) {
      float pv[16];
#pragma unroll
      for (int r = 0; r < 16; ++r) {
        float v = __builtin_amdgcn_exp2f((tile ? st1[r] : st0[r]) - mrow);
        pv[r] = v;
        rs += v;
      }
      unsigned int r0d0 = pkbf(pv[0], pv[1]),   r0d1 = pkbf(pv[2], pv[3]);
      unsigned int r1d0 = pkbf(pv[4], pv[5]),   r1d1 = pkbf(pv[6], pv[7]);
      unsigned int r2d0 = pkbf(pv[8], pv[9]),   r2d1 = pkbf(pv[10], pv[11]);
      unsigned int r3d0 = pkbf(pv[12], pv[13]), r3d1 = pkbf(pv[14], pv[15]);
      // kt_local=0: j = hi*8+0..7 -> [lo: own r0 | hi: partner r1] etc.
      asm volatile("v_permlane32_swap_b32 %0, %1" : "+v"(r0d0), "+v"(r1d0));
      asm volatile("v_permlane32_swap_b32 %0, %1" : "+v"(r0d1), "+v"(r1d1));
      pa[tile * 2] = __builtin_bit_cast(bf16x8, (u32x4){r0d0, r0d1, r1d0, r1d1});
      asm volatile("v_permlane32_swap_b32 %0, %1" : "+v"(r2d0), "+v"(r3d0));
      asm volatile("v_permlane32_swap_b32 %0, %1" : "+v"(r2d1), "+v"(r3d1));
      pa[tile * 2 + 1] =
          __builtin_bit_cast(bf16x8, (u32x4){r2d0, r2d1, r3d0, r3d1});
    }

    // O += P V : pa[kt] covers j = kt*16 + hi*8 + e; vb col=d, k=j
    __builtin_amdgcn_s_setprio(1);
#pragma unroll
    for (int kt = 0; kt < 4; ++kt) {
      int sw0 = ((kt * 2 + hi) ^ (l31 & 7)) << 3;
      bf16x8 vb0 = *(const bf16x8*)(Vs[cur] + l31 * 64 + sw0);
      bf16x8 vb1 = *(const bf16x8*)(Vs[cur] + (32 + l31) * 64 + sw0);
      oacc0 = mfma32(pa[kt], vb0, oacc0);
      oacc1 = mfma32(pa[kt], vb1, oacc1);
    }
    __builtin_amdgcn_s_setprio(0);

    __syncthreads();  // drains next-step staging + releases buf[cur]
  }

  rs += __shfl_xor(rs, 32);  // combine hi-half partial sums

  // epilogue: UNNORMALIZED partial O (bf16) + m,l per row
  size_t zb = (size_t)(z * 16 + bh) * 2048 + q0 + w * 32;
#pragma unroll
  for (int r = 0; r < 16; ++r) {
    int ql = (r & 3) + 8 * (r >> 2) + 4 * hi;
    Op[(zb + ql) * 64 + l31] = (bf16)oacc0[r];
    Op[(zb + ql) * 64 + 32 + l31] = (bf16)oacc1[r];
  }
  if (hi == 0) {
    mbuf[zb + l31] = mrow;
    lbuf[zb + l31] = rs;
  }
}

// ---------------------------------------------------------------------------
// combine: oh[row][d] = sum_z wz*O_z / sum_z wz*l_z, wz = 2^(m_z - M).
// oh ALIASES Op[z=0] (each thread reads only its own slice -> race-free).
// ---------------------------------------------------------------------------
__global__ __launch_bounds__(256) void combine(
    const bf16* __restrict__ Op, const float* __restrict__ mbuf,
    const float* __restrict__ lbuf, bf16* __restrict__ oh, int NS) {
  int idx = blockIdx.x * 256 + threadIdx.x;
  int row = idx >> 2;
  int dc = (idx & 3) * 16;

  float M = -1e30f;
  for (int z = 0; z < NS; ++z) M = fmaxf(M, mbuf[(size_t)z * 32768 + row]);

  float L = 0.0f;
  float acc[16];
#pragma unroll
  for (int e = 0; e < 16; ++e) acc[e] = 0.0f;

  for (int z = 0; z < NS; ++z) {
    float wz = __builtin_amdgcn_exp2f(mbuf[(size_t)z * 32768 + row] - M);
    L += wz * lbuf[(size_t)z * 32768 + row];
    const bf16x8* p = (const bf16x8*)(Op + ((size_t)z * 32768 + row) * 64 + dc);
#pragma unroll
    for (int v = 0; v < 2; ++v) {
      bf16x8 x = p[v];
#pragma unroll
      for (int e = 0; e < 8; ++e) acc[v * 8 + e] += wz * (float)x[e];
    }
  }
  float invL = 1.0f / L;
  bf16x8* po = (bf16x8*)(oh + (size_t)row * 64 + dc);
#pragma unroll
  for (int v = 0; v < 2; ++v) {
    bf16x8 o;
#pragma unroll
    for (int e = 0; e < 8; ++e) o[e] = (bf16)(acc[v * 8 + e] * invL);
    po[v] = o;
  }
}

// ---------------------------------------------------------------------------
// out_gemm (R6/R9 form): 128x64 tiles, single-buffer. grid (4, 32, 2).
// ---------------------------------------------------------------------------
__global__ __launch_bounds__(256) void out_gemm(
    const bf16* __restrict__ Wor, const bf16* __restrict__ oh,
    const float* __restrict__ bo, float* __restrict__ out) {
  __shared__ bf16 Al[128 * 32];
  __shared__ bf16 Bl[64 * 32];
  int b = blockIdx.z;
  int r0 = blockIdx.x * 128;
  int p0 = blockIdx.y * 64;
  int tid = threadIdx.x, w = tid >> 6, lane = tid & 63;
  int wm = w >> 1, wn = w & 1;
  int g = lane >> 4, l15 = lane & 15;

  const bf16* Abase = Wor + (size_t)r0 * 512;

  f32x4 acc[4][2] = {};

  for (int ks = 0; ks < 16; ++ks) {
    int k0 = ks * 32;
    int hh = k0 >> 6, d0 = k0 & 63;
    const bf16* Bbase = oh + (((size_t)b * 8 + hh) * 2048 + p0) * 64 + d0;
    __syncthreads();
#pragma unroll
    for (int i = 0; i < 2; ++i) {
      int rowl = w * 32 + i * 16 + (lane >> 2);
      gload_lds16(Abase + (size_t)rowl * 512 + k0 + (lane & 3) * 8,
                  Al + (w * 32 + i * 16) * 32);
    }
    {
      int browl = w * 16 + (lane >> 2);
      gload_lds16(Bbase + (size_t)browl * 64 + (lane & 3) * 8,
                  Bl + w * 16 * 32);
    }
    __syncthreads();
    bf16x8 a[4], bb[2];
#pragma unroll
    for (int mi = 0; mi < 4; ++mi)
      a[mi] = *(const bf16x8*)(Al + (wm * 64 + mi * 16 + l15) * 32 + g * 8);
#pragma unroll
    for (int ni = 0; ni < 2; ++ni)
      bb[ni] = *(const bf16x8*)(Bl + (wn * 32 + ni * 16 + l15) * 32 + g * 8);
#pragma unroll
    for (int mi = 0; mi < 4; ++mi)
#pragma unroll
      for (int ni = 0; ni < 2; ++ni)
        acc[mi][ni] = mfma16(a[mi], bb[ni], acc[mi][ni]);
  }

#pragma unroll
  for (int mi = 0; mi < 4; ++mi) {
#pragma unroll
    for (int ni = 0; ni < 2; ++ni) {
#pragma unroll
      for (int r = 0; r < 4; ++r) {
        int row = r0 + wm * 64 + mi * 16 + g * 4 + r;
        int p = p0 + wn * 32 + ni * 16 + l15;
        out[((size_t)b * 512 + row) * 2048 + p] = acc[mi][ni][r] + bo[row];
      }
    }
  }
}

// ---------------------------------------------------------------------------
extern "C" void kernel_launch(void* const* d_in, const int* in_sizes, int n_in,
                              void* d_out, int out_size, void* d_ws, size_t ws_size,
                              hipStream_t stream) {
  (void)in_sizes; (void)n_in; (void)out_size;
  const float* Q  = (const float*)d_in[0];
  const float* Wq = (const float*)d_in[1];
  const float* bq = (const float*)d_in[2];
  const float* Wk = (const float*)d_in[3];
  const float* bk = (const float*)d_in[4];
  const float* Wv = (const float*)d_in[5];
  const float* bv = (const float*)d_in[6];
  const float* Wo = (const float*)d_in[7];
  const float* bo = (const float*)d_in[8];
  float* out = (float*)d_out;

  char* ws = (char*)d_ws;
  bf16*  Wf    = (bf16*)(ws + 0);          // 1536*512*2  = 1572864
  bf16*  Wor   = (bf16*)(ws + 1572864);    // 512*512*2   = 524288
  float* biasf = (float*)(ws + 2097152);   // 1536*4      = 6144
  bf16*  Qt    = (bf16*)(ws + 2103296);    // 2*2048*512*2 = 4194304
  bf16*  qp    = (bf16*)(ws + 6297600);    // 4194304
  bf16*  kp    = (bf16*)(ws + 10491904);   // 4194304
  bf16*  vn    = (bf16*)(ws + 14686208);   // 4194304 (ends 18880512)

  size_t need4 = 18880512ull + 4ull * 4194304 + 2ull * 4ull * 131072;
  int NS = (ws_size >= need4) ? 4 : 2;
  int TS = 32 / NS;

  bf16*  Opart = (bf16*)(ws + 18880512);               // NS * 4194304 bytes
  float* mbuf  = (float*)(ws + 18880512 + (size_t)NS * 4194304);
  float* lbuf  = (float*)(ws + 18880512 + (size_t)NS * 4194304 +
                          (size_t)NS * 131072);
  bf16*  oh    = Opart;  // combine writes in place over z=0 (race-free)

  prep<<<dim3(2560), dim3(256), 0, stream>>>(Q, Wq, bq, Wk, bk, Wv, bv, Wo,
                                             Wf, biasf, Wor, Qt);
  qkv_gemm<<<dim3(12, 32, 2), dim3(256), 0, stream>>>(Wf, Qt, biasf, qp, kp, vn);
  attn_k<<<dim3(8, 16, NS), dim3(512), 0, stream>>>(qp, kp, vn, Opart, mbuf,
                                                    lbuf, TS);
  combine<<<dim3(512), dim3(256), 0, stream>>>(Opart, mbuf, lbuf, oh, NS);
  out_gemm<<<dim3(4, 32, 2), dim3(256), 0, stream>>>(Wor, oh, bo, out);
}